// Round 10
// baseline (218.747 us; speedup 1.0000x reference)
//
#include <hip/hip_runtime.h>

#define NN 100000
#define NE 1600000
#define NG 64
#define D_IN 128
#define D_H 64
#define D_H2 32
#define D_OUT 16
#define SLOPE 0.01f
#define REC 48   // slots per node; tails cleaned to NN in-LDS by consumers

#define BSH 9                     // bucket = node >> 9 (512 nodes/bucket)  [R4 proven]
#define NBK 196                   // ceil(100000/512)
#define NCB 500                   // scatter blocks (chunk 3200 edges)
#define CHE (NE / NCB)            // 3200 edges per block
#define PCAP 48                   // per-(block,bucket) cap: lambda=16.3 +7.8sigma

typedef _Float16 half2v __attribute__((ext_vector_type(2)));
typedef _Float16 h8 __attribute__((ext_vector_type(8)));
typedef float f32x4 __attribute__((ext_vector_type(4)));

// ---------- P17: LDS write-combined build scatter (R9 WIN: keep) ------------
__global__ __launch_bounds__(512) void p12_scatter(const int* __restrict__ src,
                                                   const int* __restrict__ dst,
                                                   unsigned* __restrict__ pkD,
                                                   unsigned short* __restrict__ pkS,
                                                   int* __restrict__ cntD,
                                                   int* __restrict__ cntS,
                                                   float* __restrict__ pool) {
  __shared__ unsigned stD[NBK][PCAP];          // 37.6 KB
  __shared__ unsigned short stS[NBK][PCAP];    // 18.8 KB
  __shared__ int cD[NBK], cS[NBK];
  int b = blockIdx.x, t = threadIdx.x;
  if (b == 0) {
    for (int i = t; i < NG * D_H2; i += 512) pool[i] = 0.f;
  }
  for (int i = t; i < NBK; i += 512) { cD[i] = 0; cS[i] = 0; }
  __syncthreads();
  const int4* s4 = (const int4*)(src + b * CHE);
  const int4* d4 = (const int4*)(dst + b * CHE);
  for (int i = t; i < CHE / 4; i += 512) {
    int4 s = s4[i], d = d4[i];
#pragma unroll
    for (int j = 0; j < 4; ++j) {
      int ss = (j == 0) ? s.x : (j == 1) ? s.y : (j == 2) ? s.z : s.w;
      int dd = (j == 0) ? d.x : (j == 1) ? d.y : (j == 2) ? d.z : d.w;
      int kd = dd >> BSH;
      int pd = atomicAdd(&cD[kd], 1);
      if (pd < PCAP) stD[kd][pd] = ((unsigned)(dd & 511) << 17) | (unsigned)ss;
      int ks = ss >> BSH;
      int ps = atomicAdd(&cS[ks], 1);
      if (ps < PCAP) stS[ks][ps] = (unsigned short)(ss & 511);
    }
  }
  __syncthreads();
  int wid = t >> 6, lane = t & 63;
  for (int k = wid; k < NBK; k += 8) {
    int cd = min(cD[k], PCAP), cs = min(cS[k], PCAP);
    if (lane < cd) pkD[((size_t)k * NCB + b) * PCAP + lane] = stD[k][lane];
    if (lane < cs) pkS[((size_t)k * NCB + b) * PCAP + lane] = stS[k][lane];
  }
  for (int i = t; i < NBK; i += 512) {
    cntD[i * NCB + b] = min(cD[i], PCAP);
    cntS[i * NCB + b] = min(cS[i], PCAP);
  }
}

// ---------- P3: per-bucket adjacency + indeg (dst) / outdeg (src) -----------
__global__ __launch_bounds__(512) void p3_build(const unsigned* __restrict__ pkD,
                                                const unsigned short* __restrict__ pkS,
                                                const int* __restrict__ cntD,
                                                const int* __restrict__ cntS,
                                                int* __restrict__ adj,
                                                int* __restrict__ indeg,
                                                int* __restrict__ outdeg) {
  __shared__ int hh[512];
  int bb = blockIdx.x, t = threadIdx.x;
  hh[t] = 0;
  __syncthreads();
  if (bb < NBK) {
    int k = bb;
    int n0 = k << BSH;
    if (t < NCB) {
      int cnt = cntD[k * NCB + t];
      const uint4* r4 = (const uint4*)(pkD + ((size_t)k * NCB + t) * PCAP);
      for (int i = 0; i * 4 < cnt; ++i) {
        uint4 v = r4[i];
#pragma unroll
        for (int j = 0; j < 4; ++j) {
          int idx = i * 4 + j;
          if (idx < cnt) {
            unsigned rec = (j == 0) ? v.x : (j == 1) ? v.y : (j == 2) ? v.z : v.w;
            int local = rec >> 17;
            int pos = atomicAdd(&hh[local], 1);
            if (pos < REC) adj[(size_t)(n0 + local) * REC + pos] = (int)(rec & 0x1FFFF);
          }
        }
      }
    }
    __syncthreads();
    int n = n0 + t;
    if (n < NN) indeg[n] = hh[t];
  } else {
    int k = bb - NBK;
    if (t < NCB) {
      int cnt = cntS[k * NCB + t];
      const uint4* r4 = (const uint4*)(pkS + ((size_t)k * NCB + t) * PCAP);
      for (int i = 0; i * 8 < cnt; ++i) {
        uint4 v = r4[i];
        const unsigned short* u = (const unsigned short*)&v;
#pragma unroll
        for (int j = 0; j < 8; ++j) {
          int idx = i * 8 + j;
          if (idx < cnt) atomicAdd(&hh[u[j]], 1);
        }
      }
    }
    __syncthreads();
    int n0 = k << BSH;
    int n = n0 + t;
    if (n < NN) outdeg[n] = hh[t];
  }
}

// ---------- MFMA mm1: X fp32 [N,128] @ W1 [128,64] -> fp16, rsqrt(odeg) scale
__global__ __launch_bounds__(256) void k_mm1f(const float* __restrict__ X,
                                              const float* __restrict__ W,
                                              const int* __restrict__ odeg,
                                              _Float16* __restrict__ Y) {
  __shared__ _Float16 Wt[64][136];
  int t = threadIdx.x;
  if (blockIdx.x == 0 && t < 64) Y[(size_t)NN * 64 + t] = (_Float16)0.f;
  for (int i = t; i < 128 * 64; i += 256) {
    int k = i >> 6, f = i & 63;
    Wt[f][k] = (_Float16)W[i];
  }
  __syncthreads();
  int lane = t & 63, w = t >> 6;
  int m = lane & 15, q = lane >> 4;
  h8 bf[4][4];
#pragma unroll
  for (int kc = 0; kc < 4; ++kc)
#pragma unroll
    for (int nt = 0; nt < 4; ++nt)
      bf[kc][nt] = *(const h8*)&Wt[nt * 16 + m][kc * 32 + q * 8];

  const int NT = NN / 16;  // 6250
  int idx = blockIdx.x * 4 + w;
  int t0 = idx * 2, t1 = t0 + 1;
  f32x4 r0[8], r1[8];
  if (t0 < NT) {
    const f32x4* X0 = (const f32x4*)(X + (size_t)(t0 * 16 + m) * 128);
#pragma unroll
    for (int kc = 0; kc < 4; ++kc) {
      r0[kc * 2 + 0] = X0[kc * 8 + q * 2 + 0];
      r0[kc * 2 + 1] = X0[kc * 8 + q * 2 + 1];
    }
  }
  if (t1 < NT) {
    const f32x4* X1 = (const f32x4*)(X + (size_t)(t1 * 16 + m) * 128);
#pragma unroll
    for (int kc = 0; kc < 4; ++kc) {
      r1[kc * 2 + 0] = X1[kc * 8 + q * 2 + 0];
      r1[kc * 2 + 1] = X1[kc * 8 + q * 2 + 1];
    }
  }
#pragma unroll
  for (int half = 0; half < 2; ++half) {
    int tile = (half == 0) ? t0 : t1;
    if (tile >= NT) continue;
    f32x4* rr = (half == 0) ? r0 : r1;
    f32x4 acc[4] = {{0,0,0,0},{0,0,0,0},{0,0,0,0},{0,0,0,0}};
#pragma unroll
    for (int kc = 0; kc < 4; ++kc) {
      f32x4 x0 = rr[kc * 2 + 0], x1 = rr[kc * 2 + 1];
      h8 a;
      a[0] = (_Float16)x0.x; a[1] = (_Float16)x0.y;
      a[2] = (_Float16)x0.z; a[3] = (_Float16)x0.w;
      a[4] = (_Float16)x1.x; a[5] = (_Float16)x1.y;
      a[6] = (_Float16)x1.z; a[7] = (_Float16)x1.w;
#pragma unroll
      for (int nt = 0; nt < 4; ++nt)
        acc[nt] = __builtin_amdgcn_mfma_f32_16x16x32_f16(a, bf[kc][nt], acc[nt], 0, 0, 0);
    }
    int n0 = tile * 16;
#pragma unroll
    for (int reg = 0; reg < 4; ++reg) {
      int nn = n0 + q * 4 + reg;
      float sc = rsqrtf((float)max(odeg[nn], 1));
#pragma unroll
      for (int nt = 0; nt < 4; ++nt)
        Y[(size_t)nn * 64 + nt * 16 + m] = (_Float16)(acc[nt][reg] * sc);
    }
  }
}

// ---------- fused agg + mm2: block = 64 nodes, 512 threads ------------------
// R10: R6 counters showed aggmm2 latency-bound at VALUBusy 28% with 3125
// tiny blocks (3 barriers + Wt staging each) and a phase B using 2/4 waves.
// 64 nodes/block: half the blocks, 2x gather phase per block, and phase B
// is a perfect 8-wave split (4 m-tiles x 2 n-tiles, 2 MFMAs/wave).
__global__ __launch_bounds__(512)
void k_aggmm2(const int* __restrict__ adj,
              const int* __restrict__ indeg,
              const int* __restrict__ odeg,
              const h8* __restrict__ H8,
              const float* __restrict__ W,
              _Float16* __restrict__ Y) {
  __shared__ int Adj[64][REC];      // 12.3 KB
  __shared__ int Deg[64];
  __shared__ _Float16 Ht[64][72];   // 9.2 KB
  __shared__ _Float16 Wt[32][72];   // 4.6 KB
  int t = threadIdx.x;
  if (blockIdx.x == 0 && t < 32) Y[(size_t)NN * 32 + t] = (_Float16)0.f;
  for (int i = t; i < 64 * 32; i += 512) {
    int k = i >> 5, f = i & 31;
    Wt[f][k] = (_Float16)W[i];
  }
  int node0 = blockIdx.x * 64;
  {
    int maxi = (min(NN - node0, 64)) * (REC / 4);
    const int4* gadj = (const int4*)(adj + (size_t)node0 * REC);
    for (int i = t; i < 64 * (REC / 4); i += 512)
      ((int4*)Adj)[i] = (i < maxi) ? gadj[i] : make_int4(NN, NN, NN, NN);
    if (t < 64) Deg[t] = (node0 + t < NN) ? indeg[node0 + t] : 0;
  }
  __syncthreads();
  // clean tail slots (garbage -> phantom NN); 64*48/512 = 6 iterations
  for (int i = t; i < 64 * REC; i += 512) {
    int ndc = i / REC, j = i % REC;
    if (j >= min(Deg[ndc], REC)) Adj[ndc][j] = NN;
  }
  __syncthreads();
  // phase A: gather + accumulate
  int l8 = t & 7;                 // feature octet (8 halves = 16B)
  int nd = t >> 3;                // node in block, 0..63
  int deg = Deg[nd];
  int groups = (min(deg, REC) + 15) >> 4;
  float acc[8] = {0.f, 0.f, 0.f, 0.f, 0.f, 0.f, 0.f, 0.f};
  for (int g = 0; g < groups; ++g) {
    int4 c0 = *(const int4*)&Adj[nd][g * 16 + 0];
    int4 c1 = *(const int4*)&Adj[nd][g * 16 + 4];
    int4 c2 = *(const int4*)&Adj[nd][g * 16 + 8];
    int4 c3 = *(const int4*)&Adj[nd][g * 16 + 12];
    h8 v0 = H8[(size_t)c0.x * 8 + l8];
    h8 v1 = H8[(size_t)c0.y * 8 + l8];
    h8 v2 = H8[(size_t)c0.z * 8 + l8];
    h8 v3 = H8[(size_t)c0.w * 8 + l8];
    h8 v4 = H8[(size_t)c1.x * 8 + l8];
    h8 v5 = H8[(size_t)c1.y * 8 + l8];
    h8 v6 = H8[(size_t)c1.z * 8 + l8];
    h8 v7 = H8[(size_t)c1.w * 8 + l8];
    h8 v8 = H8[(size_t)c2.x * 8 + l8];
    h8 v9 = H8[(size_t)c2.y * 8 + l8];
    h8 va = H8[(size_t)c2.z * 8 + l8];
    h8 vb = H8[(size_t)c2.w * 8 + l8];
    h8 vc = H8[(size_t)c3.x * 8 + l8];
    h8 vd = H8[(size_t)c3.y * 8 + l8];
    h8 ve = H8[(size_t)c3.z * 8 + l8];
    h8 vf = H8[(size_t)c3.w * 8 + l8];
#pragma unroll
    for (int j = 0; j < 8; ++j)
      acc[j] += ((((float)v0[j] + (float)v1[j]) + ((float)v2[j] + (float)v3[j])) +
                 (((float)v4[j] + (float)v5[j]) + ((float)v6[j] + (float)v7[j]))) +
                ((((float)v8[j] + (float)v9[j]) + ((float)va[j] + (float)vb[j])) +
                 (((float)vc[j] + (float)vd[j]) + ((float)ve[j] + (float)vf[j])));
  }
  float sc = rsqrtf((float)max(deg, 1));
  h8 hv;
#pragma unroll
  for (int j = 0; j < 8; ++j) {
    float x = acc[j] * sc;
    hv[j] = (_Float16)((x > 0.f) ? x : SLOPE * x);
  }
  *(h8*)&Ht[nd][l8 * 8] = hv;
  __syncthreads();
  // phase B: 8 waves, wave w -> m-tile (w>>1), n-half (w&1); 2 MFMAs each
  int lane = t & 63, w = t >> 6;
  int mtile = w >> 1, ntv = w & 1;
  int m = lane & 15, q = lane >> 4;
  h8 bf[2], af[2];
#pragma unroll
  for (int kc = 0; kc < 2; ++kc) {
    bf[kc] = *(const h8*)&Wt[ntv * 16 + m][kc * 32 + q * 8];
    af[kc] = *(const h8*)&Ht[mtile * 16 + m][kc * 32 + q * 8];
  }
  f32x4 acc2 = {0, 0, 0, 0};
#pragma unroll
  for (int kc = 0; kc < 2; ++kc)
    acc2 = __builtin_amdgcn_mfma_f32_16x16x32_f16(af[kc], bf[kc], acc2, 0, 0, 0);
#pragma unroll
  for (int reg = 0; reg < 4; ++reg) {
    int nn = node0 + mtile * 16 + q * 4 + reg;
    if (nn < NN) {
      float sco = rsqrtf((float)max(odeg[nn], 1));
      Y[(size_t)nn * 32 + ntv * 16 + m] = (_Float16)(acc2[reg] * sco);
    }
  }
}

// ---------- fused layer-2 aggregation + per-graph pool partials -------------
__global__ __launch_bounds__(256)
void k_agg32p(const int* __restrict__ adj,
              const int* __restrict__ indeg,
              const int* __restrict__ gid,
              const h8* __restrict__ H8,
              float* __restrict__ pool) {
  __shared__ int Adj2[64][REC];    // 12 KB
  __shared__ int Deg2[64];
  __shared__ float lp[4][D_H2];
  __shared__ int gmin_s;
  int t = threadIdx.x;
  int l4 = t & 3;                  // feature octet (8 halves = 16B)
  int nd = t >> 2;                 // node in block, 0..63
  int node0 = blockIdx.x * 64;
  int node = node0 + nd;
  bool valid = node < NN;
  if (t == 0) gmin_s = gid[node0];
  for (int i = t; i < 4 * D_H2; i += 256) ((float*)lp)[i] = 0.f;
  {
    int maxi = (min(NN - node0, 64)) * (REC / 4);
    const int4* gadj = (const int4*)(adj + (size_t)node0 * REC);
    for (int i = t; i < 64 * (REC / 4); i += 256)
      ((int4*)Adj2)[i] = (i < maxi) ? gadj[i] : make_int4(NN, NN, NN, NN);
    if (t < 64) Deg2[t] = (node0 + t < NN) ? indeg[node0 + t] : 0;
  }
  __syncthreads();  // Adj2/Deg2 staged, lp zeroed, gmin_s set
  // clean tail slots (garbage -> phantom NN); 64*48/256 = 12 iterations
  for (int i = t; i < 64 * REC; i += 256) {
    int ndc = i / REC, j = i % REC;
    if (j >= min(Deg2[ndc], REC)) Adj2[ndc][j] = NN;
  }
  __syncthreads();
  int deg = Deg2[nd];
  int groups = (min(deg, REC) + 15) >> 4;
  float acc[8] = {0.f, 0.f, 0.f, 0.f, 0.f, 0.f, 0.f, 0.f};
  for (int g = 0; g < groups; ++g) {
    int4 c0 = *(const int4*)&Adj2[nd][g * 16 + 0];
    int4 c1 = *(const int4*)&Adj2[nd][g * 16 + 4];
    int4 c2 = *(const int4*)&Adj2[nd][g * 16 + 8];
    int4 c3 = *(const int4*)&Adj2[nd][g * 16 + 12];
    h8 v0 = H8[(size_t)c0.x * 4 + l4];
    h8 v1 = H8[(size_t)c0.y * 4 + l4];
    h8 v2 = H8[(size_t)c0.z * 4 + l4];
    h8 v3 = H8[(size_t)c0.w * 4 + l4];
    h8 v4 = H8[(size_t)c1.x * 4 + l4];
    h8 v5 = H8[(size_t)c1.y * 4 + l4];
    h8 v6 = H8[(size_t)c1.z * 4 + l4];
    h8 v7 = H8[(size_t)c1.w * 4 + l4];
    h8 v8 = H8[(size_t)c2.x * 4 + l4];
    h8 v9 = H8[(size_t)c2.y * 4 + l4];
    h8 va = H8[(size_t)c2.z * 4 + l4];
    h8 vb = H8[(size_t)c2.w * 4 + l4];
    h8 vc = H8[(size_t)c3.x * 4 + l4];
    h8 vd = H8[(size_t)c3.y * 4 + l4];
    h8 ve = H8[(size_t)c3.z * 4 + l4];
    h8 vf = H8[(size_t)c3.w * 4 + l4];
#pragma unroll
    for (int j = 0; j < 8; ++j)
      acc[j] += ((((float)v0[j] + (float)v1[j]) + ((float)v2[j] + (float)v3[j])) +
                 (((float)v4[j] + (float)v5[j]) + ((float)v6[j] + (float)v7[j]))) +
                ((((float)v8[j] + (float)v9[j]) + ((float)va[j] + (float)vb[j])) +
                 (((float)vc[j] + (float)vd[j]) + ((float)ve[j] + (float)vf[j])));
  }
  if (valid) {
    float sc = rsqrtf((float)max(deg, 1));
    int gl = min(gid[node] - gmin_s, 3);
#pragma unroll
    for (int j = 0; j < 8; ++j) {
      float x = acc[j] * sc;
      x = (x > 0.f) ? x : SLOPE * x;   // h3 element, fp32
      atomicAdd(&lp[gl][l4 * 8 + j], x);
    }
  }
  __syncthreads();
  // flush: thread i of first 128 covers (gl, feat)
  if (t < 4 * D_H2) {
    float v = ((float*)lp)[t];
    if (v != 0.f) {
      int gl = t >> 5, f = t & 31;
      atomicAdd(&pool[(gmin_s + gl) * D_H2 + f], v);
    }
  }
}

// ---------- final: counts via binary search, mean, @ Wc ---------------------
__global__ __launch_bounds__(256) void k_out(const float* __restrict__ pool,
                                             const int* __restrict__ gid,
                                             const float* __restrict__ Wc,
                                             float* __restrict__ out) {
  __shared__ int bnd[NG + 1];
  __shared__ float mean[NG][D_H2];
  int t = threadIdx.x;
  if (t <= NG) {
    int target = t;  // lower_bound(gid, target)
    int lo = 0, hi = NN;
    while (lo < hi) {
      int mid = (lo + hi) >> 1;
      if (gid[mid] < target) lo = mid + 1; else hi = mid;
    }
    bnd[t] = lo;
  }
  __syncthreads();
  for (int i = t; i < NG * D_H2; i += 256) {
    int g = i >> 5;
    float inv = 1.0f / (float)max(bnd[g + 1] - bnd[g], 1);
    ((float*)mean)[i] = pool[i] * inv;
  }
  __syncthreads();
  for (int i = t; i < NG * D_OUT; i += 256) {
    int g = i / D_OUT, o = i % D_OUT;
    float s = 0.f;
#pragma unroll
    for (int c = 0; c < D_H2; ++c) s += mean[g][c] * Wc[c * D_OUT + o];
    out[i] = s;
  }
}

extern "C" void kernel_launch(void* const* d_in, const int* in_sizes, int n_in,
                              void* d_out, int out_size, void* d_ws, size_t ws_size,
                              hipStream_t stream) {
  const float* X  = (const float*)d_in[0];
  const int*   src = (const int*)d_in[1];
  const int*   dst = (const int*)d_in[2];
  const int*   gid = (const int*)d_in[3];
  const float* W1 = (const float*)d_in[4];
  const float* W2 = (const float*)d_in[5];
  const float* Wc = (const float*)d_in[6];
  float* out = (float*)d_out;

  char* p = (char*)d_ws;
  auto alloc = [&](size_t bytes) {
    char* q = p;
    p += (bytes + 255) & ~(size_t)255;
    return q;
  };
  float*          pool   = (float*)alloc(NG * D_H2 * 4);                 // 8 KB
  int*            outdeg = (int*)alloc(NN * 4);
  int*            indeg  = (int*)alloc(NN * 4);
  int*            cntD   = (int*)alloc((size_t)NBK * NCB * 4);           // 392 KB
  int*            cntS   = (int*)alloc((size_t)NBK * NCB * 4);           // 392 KB
  unsigned*       pkD    = (unsigned*)alloc((size_t)NBK * NCB * PCAP * 4);       // 18.8 MB
  unsigned short* pkS    = (unsigned short*)alloc((size_t)NBK * NCB * PCAP * 2); // 9.4 MB
  int*            adj    = (int*)alloc((size_t)NN * REC * 4);            // 19.2 MB
  _Float16*       bufA   = (_Float16*)alloc((size_t)(NN + 1) * 64 * 2);  // h0 (+phantom)
  _Float16*       bufC   = (_Float16*)alloc((size_t)(NN + 1) * 32 * 2);  // h2 (+phantom)

  // single-pass build into private (block,bucket) regions (pool zeroed inside)
  p12_scatter<<<NCB, 512, 0, stream>>>(src, dst, pkD, pkS, cntD, cntS, pool);
  p3_build<<<2 * NBK, 512, 0, stream>>>(pkD, pkS, cntD, cntS, adj, indeg, outdeg);

  // layer 1 matmul: h0 = (X @ W1) * rsqrt(outdeg)   (phantom row zeroed)
  k_mm1f<<<782, 256, 0, stream>>>(X, W1, outdeg, bufA);
  // fused: h1 = leaky(rsqrt(indeg) * A h0); h2 = (h1 @ W2) * rsqrt(outdeg)
  k_aggmm2<<<(NN + 63) / 64, 512, 0, stream>>>(adj, indeg, outdeg, (const h8*)bufA, W2, bufC);
  // fused: h3 = leaky(rsqrt(indeg) * A h2) -> per-graph pool partials (no h3 in HBM)
  k_agg32p<<<(NN + 63) / 64, 256, 0, stream>>>(adj, indeg, gid, (const h8*)bufC, pool);
  // final: counts, mean, readout
  k_out<<<1, 256, 0, stream>>>(pool, gid, Wc, out);
}

// Round 11
// 211.246 us; speedup vs baseline: 1.0355x; 1.0355x over previous
//
#include <hip/hip_runtime.h>

#define NN 100000
#define NE 1600000
#define NG 64
#define D_IN 128
#define D_H 64
#define D_H2 32
#define D_OUT 16
#define SLOPE 0.01f
#define REC 48   // slots per node; tails cleaned to NN in-LDS by consumers

#define BSH 9                     // bucket = node >> 9 (512 nodes/bucket)  [R4 proven]
#define NBK 196                   // ceil(100000/512)
#define NCB 500                   // scatter blocks (chunk 3200 edges)
#define CHE (NE / NCB)            // 3200 edges per block
#define PCAP 48                   // per-(block,bucket) cap: lambda=16.3 +7.8sigma

typedef _Float16 half2v __attribute__((ext_vector_type(2)));
typedef _Float16 h8 __attribute__((ext_vector_type(8)));
typedef float f32x4 __attribute__((ext_vector_type(4)));

// ---------- P17: LDS write-combined build scatter (R9 WIN: keep) ------------
__global__ __launch_bounds__(512) void p12_scatter(const int* __restrict__ src,
                                                   const int* __restrict__ dst,
                                                   unsigned* __restrict__ pkD,
                                                   unsigned short* __restrict__ pkS,
                                                   int* __restrict__ cntD,
                                                   int* __restrict__ cntS,
                                                   float* __restrict__ pool) {
  __shared__ unsigned stD[NBK][PCAP];          // 37.6 KB
  __shared__ unsigned short stS[NBK][PCAP];    // 18.8 KB
  __shared__ int cD[NBK], cS[NBK];
  int b = blockIdx.x, t = threadIdx.x;
  if (b == 0) {
    for (int i = t; i < NG * D_H2; i += 512) pool[i] = 0.f;
  }
  for (int i = t; i < NBK; i += 512) { cD[i] = 0; cS[i] = 0; }
  __syncthreads();
  const int4* s4 = (const int4*)(src + b * CHE);
  const int4* d4 = (const int4*)(dst + b * CHE);
  for (int i = t; i < CHE / 4; i += 512) {
    int4 s = s4[i], d = d4[i];
#pragma unroll
    for (int j = 0; j < 4; ++j) {
      int ss = (j == 0) ? s.x : (j == 1) ? s.y : (j == 2) ? s.z : s.w;
      int dd = (j == 0) ? d.x : (j == 1) ? d.y : (j == 2) ? d.z : d.w;
      int kd = dd >> BSH;
      int pd = atomicAdd(&cD[kd], 1);
      if (pd < PCAP) stD[kd][pd] = ((unsigned)(dd & 511) << 17) | (unsigned)ss;
      int ks = ss >> BSH;
      int ps = atomicAdd(&cS[ks], 1);
      if (ps < PCAP) stS[ks][ps] = (unsigned short)(ss & 511);
    }
  }
  __syncthreads();
  int wid = t >> 6, lane = t & 63;
  for (int k = wid; k < NBK; k += 8) {
    int cd = min(cD[k], PCAP), cs = min(cS[k], PCAP);
    if (lane < cd) pkD[((size_t)k * NCB + b) * PCAP + lane] = stD[k][lane];
    if (lane < cs) pkS[((size_t)k * NCB + b) * PCAP + lane] = stS[k][lane];
  }
  for (int i = t; i < NBK; i += 512) {
    cntD[i * NCB + b] = min(cD[i], PCAP);
    cntS[i * NCB + b] = min(cS[i], PCAP);
  }
}

// ---------- P3: per-bucket adjacency + indeg (dst) / outdeg (src) -----------
__global__ __launch_bounds__(512) void p3_build(const unsigned* __restrict__ pkD,
                                                const unsigned short* __restrict__ pkS,
                                                const int* __restrict__ cntD,
                                                const int* __restrict__ cntS,
                                                int* __restrict__ adj,
                                                int* __restrict__ indeg,
                                                int* __restrict__ outdeg) {
  __shared__ int hh[512];
  int bb = blockIdx.x, t = threadIdx.x;
  hh[t] = 0;
  __syncthreads();
  if (bb < NBK) {
    int k = bb;
    int n0 = k << BSH;
    if (t < NCB) {
      int cnt = cntD[k * NCB + t];
      const uint4* r4 = (const uint4*)(pkD + ((size_t)k * NCB + t) * PCAP);
      for (int i = 0; i * 4 < cnt; ++i) {
        uint4 v = r4[i];
#pragma unroll
        for (int j = 0; j < 4; ++j) {
          int idx = i * 4 + j;
          if (idx < cnt) {
            unsigned rec = (j == 0) ? v.x : (j == 1) ? v.y : (j == 2) ? v.z : v.w;
            int local = rec >> 17;
            int pos = atomicAdd(&hh[local], 1);
            if (pos < REC) adj[(size_t)(n0 + local) * REC + pos] = (int)(rec & 0x1FFFF);
          }
        }
      }
    }
    __syncthreads();
    int n = n0 + t;
    if (n < NN) indeg[n] = hh[t];
  } else {
    int k = bb - NBK;
    if (t < NCB) {
      int cnt = cntS[k * NCB + t];
      const uint4* r4 = (const uint4*)(pkS + ((size_t)k * NCB + t) * PCAP);
      for (int i = 0; i * 8 < cnt; ++i) {
        uint4 v = r4[i];
        const unsigned short* u = (const unsigned short*)&v;
#pragma unroll
        for (int j = 0; j < 8; ++j) {
          int idx = i * 8 + j;
          if (idx < cnt) atomicAdd(&hh[u[j]], 1);
        }
      }
    }
    __syncthreads();
    int n0 = k << BSH;
    int n = n0 + t;
    if (n < NN) outdeg[n] = hh[t];
  }
}

// ---------- MFMA mm1: X fp32 [N,128] @ W1 [128,64] -> fp16, rsqrt(odeg) scale
__global__ __launch_bounds__(256) void k_mm1f(const float* __restrict__ X,
                                              const float* __restrict__ W,
                                              const int* __restrict__ odeg,
                                              _Float16* __restrict__ Y) {
  __shared__ _Float16 Wt[64][136];
  int t = threadIdx.x;
  if (blockIdx.x == 0 && t < 64) Y[(size_t)NN * 64 + t] = (_Float16)0.f;
  for (int i = t; i < 128 * 64; i += 256) {
    int k = i >> 6, f = i & 63;
    Wt[f][k] = (_Float16)W[i];
  }
  __syncthreads();
  int lane = t & 63, w = t >> 6;
  int m = lane & 15, q = lane >> 4;
  h8 bf[4][4];
#pragma unroll
  for (int kc = 0; kc < 4; ++kc)
#pragma unroll
    for (int nt = 0; nt < 4; ++nt)
      bf[kc][nt] = *(const h8*)&Wt[nt * 16 + m][kc * 32 + q * 8];

  const int NT = NN / 16;  // 6250
  int idx = blockIdx.x * 4 + w;
  int t0 = idx * 2, t1 = t0 + 1;
  f32x4 r0[8], r1[8];
  if (t0 < NT) {
    const f32x4* X0 = (const f32x4*)(X + (size_t)(t0 * 16 + m) * 128);
#pragma unroll
    for (int kc = 0; kc < 4; ++kc) {
      r0[kc * 2 + 0] = X0[kc * 8 + q * 2 + 0];
      r0[kc * 2 + 1] = X0[kc * 8 + q * 2 + 1];
    }
  }
  if (t1 < NT) {
    const f32x4* X1 = (const f32x4*)(X + (size_t)(t1 * 16 + m) * 128);
#pragma unroll
    for (int kc = 0; kc < 4; ++kc) {
      r1[kc * 2 + 0] = X1[kc * 8 + q * 2 + 0];
      r1[kc * 2 + 1] = X1[kc * 8 + q * 2 + 1];
    }
  }
#pragma unroll
  for (int half = 0; half < 2; ++half) {
    int tile = (half == 0) ? t0 : t1;
    if (tile >= NT) continue;
    f32x4* rr = (half == 0) ? r0 : r1;
    f32x4 acc[4] = {{0,0,0,0},{0,0,0,0},{0,0,0,0},{0,0,0,0}};
#pragma unroll
    for (int kc = 0; kc < 4; ++kc) {
      f32x4 x0 = rr[kc * 2 + 0], x1 = rr[kc * 2 + 1];
      h8 a;
      a[0] = (_Float16)x0.x; a[1] = (_Float16)x0.y;
      a[2] = (_Float16)x0.z; a[3] = (_Float16)x0.w;
      a[4] = (_Float16)x1.x; a[5] = (_Float16)x1.y;
      a[6] = (_Float16)x1.z; a[7] = (_Float16)x1.w;
#pragma unroll
      for (int nt = 0; nt < 4; ++nt)
        acc[nt] = __builtin_amdgcn_mfma_f32_16x16x32_f16(a, bf[kc][nt], acc[nt], 0, 0, 0);
    }
    int n0 = tile * 16;
#pragma unroll
    for (int reg = 0; reg < 4; ++reg) {
      int nn = n0 + q * 4 + reg;
      float sc = rsqrtf((float)max(odeg[nn], 1));
#pragma unroll
      for (int nt = 0; nt < 4; ++nt)
        Y[(size_t)nn * 64 + nt * 16 + m] = (_Float16)(acc[nt][reg] * sc);
    }
  }
}

// ---------- fused agg + mm2: block = 16 nodes, 128 threads ------------------
// R11: block-size gradient from measurements: 64n/512t = 46.5us (R10),
// 32n/256t = 40.4us (R6/R9). Probe 16n/128t: 2-wave barriers, 16 resident
// blocks/CU (thread cap; LDS ~10KB x16 = 160KB fits), phase B uses ALL
// waves (2 waves x 2 col-tiles, 2 MFMAs each).
__global__ __launch_bounds__(128)
void k_aggmm2(const int* __restrict__ adj,
              const int* __restrict__ indeg,
              const int* __restrict__ odeg,
              const h8* __restrict__ H8,
              const float* __restrict__ W,
              _Float16* __restrict__ Y) {
  __shared__ int Adj[16][REC];      // 3 KB
  __shared__ int Deg[16];
  __shared__ _Float16 Ht[16][72];   // 2.25 KB
  __shared__ _Float16 Wt[32][72];   // 4.5 KB
  int t = threadIdx.x;
  if (blockIdx.x == 0 && t < 32) Y[(size_t)NN * 32 + t] = (_Float16)0.f;
  for (int i = t; i < 64 * 32; i += 128) {
    int k = i >> 5, f = i & 31;
    Wt[f][k] = (_Float16)W[i];
  }
  int node0 = blockIdx.x * 16;   // NN % 16 == 0: blocks exactly cover
  {
    const int4* gadj = (const int4*)(adj + (size_t)node0 * REC);
    for (int i = t; i < 16 * (REC / 4); i += 128)
      ((int4*)Adj)[i] = gadj[i];
    if (t < 16) Deg[t] = indeg[node0 + t];
  }
  __syncthreads();
  // clean tail slots (garbage -> phantom NN); 16*48/128 = 6 iterations
  for (int i = t; i < 16 * REC; i += 128) {
    int ndc = i / REC, j = i % REC;
    if (j >= min(Deg[ndc], REC)) Adj[ndc][j] = NN;
  }
  __syncthreads();
  // phase A: gather + accumulate (8 threads/node, 16B octets)
  int l8 = t & 7;
  int nd = t >> 3;                // node in block, 0..15
  int deg = Deg[nd];
  int groups = (min(deg, REC) + 15) >> 4;
  float acc[8] = {0.f, 0.f, 0.f, 0.f, 0.f, 0.f, 0.f, 0.f};
  for (int g = 0; g < groups; ++g) {
    int4 c0 = *(const int4*)&Adj[nd][g * 16 + 0];
    int4 c1 = *(const int4*)&Adj[nd][g * 16 + 4];
    int4 c2 = *(const int4*)&Adj[nd][g * 16 + 8];
    int4 c3 = *(const int4*)&Adj[nd][g * 16 + 12];
    h8 v0 = H8[(size_t)c0.x * 8 + l8];
    h8 v1 = H8[(size_t)c0.y * 8 + l8];
    h8 v2 = H8[(size_t)c0.z * 8 + l8];
    h8 v3 = H8[(size_t)c0.w * 8 + l8];
    h8 v4 = H8[(size_t)c1.x * 8 + l8];
    h8 v5 = H8[(size_t)c1.y * 8 + l8];
    h8 v6 = H8[(size_t)c1.z * 8 + l8];
    h8 v7 = H8[(size_t)c1.w * 8 + l8];
    h8 v8 = H8[(size_t)c2.x * 8 + l8];
    h8 v9 = H8[(size_t)c2.y * 8 + l8];
    h8 va = H8[(size_t)c2.z * 8 + l8];
    h8 vb = H8[(size_t)c2.w * 8 + l8];
    h8 vc = H8[(size_t)c3.x * 8 + l8];
    h8 vd = H8[(size_t)c3.y * 8 + l8];
    h8 ve = H8[(size_t)c3.z * 8 + l8];
    h8 vf = H8[(size_t)c3.w * 8 + l8];
#pragma unroll
    for (int j = 0; j < 8; ++j)
      acc[j] += ((((float)v0[j] + (float)v1[j]) + ((float)v2[j] + (float)v3[j])) +
                 (((float)v4[j] + (float)v5[j]) + ((float)v6[j] + (float)v7[j]))) +
                ((((float)v8[j] + (float)v9[j]) + ((float)va[j] + (float)vb[j])) +
                 (((float)vc[j] + (float)vd[j]) + ((float)ve[j] + (float)vf[j])));
  }
  float sc = rsqrtf((float)max(deg, 1));
  h8 hv;
#pragma unroll
  for (int j = 0; j < 8; ++j) {
    float x = acc[j] * sc;
    hv[j] = (_Float16)((x > 0.f) ? x : SLOPE * x);
  }
  *(h8*)&Ht[nd][l8 * 8] = hv;
  __syncthreads();
  // phase B: 2 waves, wave w -> col-tile w; A = all 16 node-rows
  int lane = t & 63, w = t >> 6;
  int m = lane & 15, q = lane >> 4;
  h8 bf[2], af[2];
#pragma unroll
  for (int kc = 0; kc < 2; ++kc) {
    bf[kc] = *(const h8*)&Wt[w * 16 + m][kc * 32 + q * 8];
    af[kc] = *(const h8*)&Ht[m][kc * 32 + q * 8];
  }
  f32x4 acc2 = {0, 0, 0, 0};
#pragma unroll
  for (int kc = 0; kc < 2; ++kc)
    acc2 = __builtin_amdgcn_mfma_f32_16x16x32_f16(af[kc], bf[kc], acc2, 0, 0, 0);
#pragma unroll
  for (int reg = 0; reg < 4; ++reg) {
    int nn = node0 + q * 4 + reg;
    float sco = rsqrtf((float)max(odeg[nn], 1));
    Y[(size_t)nn * 32 + w * 16 + m] = (_Float16)(acc2[reg] * sco);
  }
}

// ---------- fused layer-2 aggregation + per-graph pool partials -------------
__global__ __launch_bounds__(256)
void k_agg32p(const int* __restrict__ adj,
              const int* __restrict__ indeg,
              const int* __restrict__ gid,
              const h8* __restrict__ H8,
              float* __restrict__ pool) {
  __shared__ int Adj2[64][REC];    // 12 KB
  __shared__ int Deg2[64];
  __shared__ float lp[4][D_H2];
  __shared__ int gmin_s;
  int t = threadIdx.x;
  int l4 = t & 3;                  // feature octet (8 halves = 16B)
  int nd = t >> 2;                 // node in block, 0..63
  int node0 = blockIdx.x * 64;
  int node = node0 + nd;
  bool valid = node < NN;
  if (t == 0) gmin_s = gid[node0];
  for (int i = t; i < 4 * D_H2; i += 256) ((float*)lp)[i] = 0.f;
  {
    int maxi = (min(NN - node0, 64)) * (REC / 4);
    const int4* gadj = (const int4*)(adj + (size_t)node0 * REC);
    for (int i = t; i < 64 * (REC / 4); i += 256)
      ((int4*)Adj2)[i] = (i < maxi) ? gadj[i] : make_int4(NN, NN, NN, NN);
    if (t < 64) Deg2[t] = (node0 + t < NN) ? indeg[node0 + t] : 0;
  }
  __syncthreads();  // Adj2/Deg2 staged, lp zeroed, gmin_s set
  // clean tail slots (garbage -> phantom NN); 64*48/256 = 12 iterations
  for (int i = t; i < 64 * REC; i += 256) {
    int ndc = i / REC, j = i % REC;
    if (j >= min(Deg2[ndc], REC)) Adj2[ndc][j] = NN;
  }
  __syncthreads();
  int deg = Deg2[nd];
  int groups = (min(deg, REC) + 15) >> 4;
  float acc[8] = {0.f, 0.f, 0.f, 0.f, 0.f, 0.f, 0.f, 0.f};
  for (int g = 0; g < groups; ++g) {
    int4 c0 = *(const int4*)&Adj2[nd][g * 16 + 0];
    int4 c1 = *(const int4*)&Adj2[nd][g * 16 + 4];
    int4 c2 = *(const int4*)&Adj2[nd][g * 16 + 8];
    int4 c3 = *(const int4*)&Adj2[nd][g * 16 + 12];
    h8 v0 = H8[(size_t)c0.x * 4 + l4];
    h8 v1 = H8[(size_t)c0.y * 4 + l4];
    h8 v2 = H8[(size_t)c0.z * 4 + l4];
    h8 v3 = H8[(size_t)c0.w * 4 + l4];
    h8 v4 = H8[(size_t)c1.x * 4 + l4];
    h8 v5 = H8[(size_t)c1.y * 4 + l4];
    h8 v6 = H8[(size_t)c1.z * 4 + l4];
    h8 v7 = H8[(size_t)c1.w * 4 + l4];
    h8 v8 = H8[(size_t)c2.x * 4 + l4];
    h8 v9 = H8[(size_t)c2.y * 4 + l4];
    h8 va = H8[(size_t)c2.z * 4 + l4];
    h8 vb = H8[(size_t)c2.w * 4 + l4];
    h8 vc = H8[(size_t)c3.x * 4 + l4];
    h8 vd = H8[(size_t)c3.y * 4 + l4];
    h8 ve = H8[(size_t)c3.z * 4 + l4];
    h8 vf = H8[(size_t)c3.w * 4 + l4];
#pragma unroll
    for (int j = 0; j < 8; ++j)
      acc[j] += ((((float)v0[j] + (float)v1[j]) + ((float)v2[j] + (float)v3[j])) +
                 (((float)v4[j] + (float)v5[j]) + ((float)v6[j] + (float)v7[j]))) +
                ((((float)v8[j] + (float)v9[j]) + ((float)va[j] + (float)vb[j])) +
                 (((float)vc[j] + (float)vd[j]) + ((float)ve[j] + (float)vf[j])));
  }
  if (valid) {
    float sc = rsqrtf((float)max(deg, 1));
    int gl = min(gid[node] - gmin_s, 3);
#pragma unroll
    for (int j = 0; j < 8; ++j) {
      float x = acc[j] * sc;
      x = (x > 0.f) ? x : SLOPE * x;   // h3 element, fp32
      atomicAdd(&lp[gl][l4 * 8 + j], x);
    }
  }
  __syncthreads();
  // flush: thread i of first 128 covers (gl, feat)
  if (t < 4 * D_H2) {
    float v = ((float*)lp)[t];
    if (v != 0.f) {
      int gl = t >> 5, f = t & 31;
      atomicAdd(&pool[(gmin_s + gl) * D_H2 + f], v);
    }
  }
}

// ---------- final: counts via binary search, mean, @ Wc ---------------------
__global__ __launch_bounds__(256) void k_out(const float* __restrict__ pool,
                                             const int* __restrict__ gid,
                                             const float* __restrict__ Wc,
                                             float* __restrict__ out) {
  __shared__ int bnd[NG + 1];
  __shared__ float mean[NG][D_H2];
  int t = threadIdx.x;
  if (t <= NG) {
    int target = t;  // lower_bound(gid, target)
    int lo = 0, hi = NN;
    while (lo < hi) {
      int mid = (lo + hi) >> 1;
      if (gid[mid] < target) lo = mid + 1; else hi = mid;
    }
    bnd[t] = lo;
  }
  __syncthreads();
  for (int i = t; i < NG * D_H2; i += 256) {
    int g = i >> 5;
    float inv = 1.0f / (float)max(bnd[g + 1] - bnd[g], 1);
    ((float*)mean)[i] = pool[i] * inv;
  }
  __syncthreads();
  for (int i = t; i < NG * D_OUT; i += 256) {
    int g = i / D_OUT, o = i % D_OUT;
    float s = 0.f;
#pragma unroll
    for (int c = 0; c < D_H2; ++c) s += mean[g][c] * Wc[c * D_OUT + o];
    out[i] = s;
  }
}

extern "C" void kernel_launch(void* const* d_in, const int* in_sizes, int n_in,
                              void* d_out, int out_size, void* d_ws, size_t ws_size,
                              hipStream_t stream) {
  const float* X  = (const float*)d_in[0];
  const int*   src = (const int*)d_in[1];
  const int*   dst = (const int*)d_in[2];
  const int*   gid = (const int*)d_in[3];
  const float* W1 = (const float*)d_in[4];
  const float* W2 = (const float*)d_in[5];
  const float* Wc = (const float*)d_in[6];
  float* out = (float*)d_out;

  char* p = (char*)d_ws;
  auto alloc = [&](size_t bytes) {
    char* q = p;
    p += (bytes + 255) & ~(size_t)255;
    return q;
  };
  float*          pool   = (float*)alloc(NG * D_H2 * 4);                 // 8 KB
  int*            outdeg = (int*)alloc(NN * 4);
  int*            indeg  = (int*)alloc(NN * 4);
  int*            cntD   = (int*)alloc((size_t)NBK * NCB * 4);           // 392 KB
  int*            cntS   = (int*)alloc((size_t)NBK * NCB * 4);           // 392 KB
  unsigned*       pkD    = (unsigned*)alloc((size_t)NBK * NCB * PCAP * 4);       // 18.8 MB
  unsigned short* pkS    = (unsigned short*)alloc((size_t)NBK * NCB * PCAP * 2); // 9.4 MB
  int*            adj    = (int*)alloc((size_t)NN * REC * 4);            // 19.2 MB
  _Float16*       bufA   = (_Float16*)alloc((size_t)(NN + 1) * 64 * 2);  // h0 (+phantom)
  _Float16*       bufC   = (_Float16*)alloc((size_t)(NN + 1) * 32 * 2);  // h2 (+phantom)

  // single-pass build into private (block,bucket) regions (pool zeroed inside)
  p12_scatter<<<NCB, 512, 0, stream>>>(src, dst, pkD, pkS, cntD, cntS, pool);
  p3_build<<<2 * NBK, 512, 0, stream>>>(pkD, pkS, cntD, cntS, adj, indeg, outdeg);

  // layer 1 matmul: h0 = (X @ W1) * rsqrt(outdeg)   (phantom row zeroed)
  k_mm1f<<<782, 256, 0, stream>>>(X, W1, outdeg, bufA);
  // fused: h1 = leaky(rsqrt(indeg) * A h0); h2 = (h1 @ W2) * rsqrt(outdeg)
  k_aggmm2<<<NN / 16, 128, 0, stream>>>(adj, indeg, outdeg, (const h8*)bufA, W2, bufC);
  // fused: h3 = leaky(rsqrt(indeg) * A h2) -> per-graph pool partials (no h3 in HBM)
  k_agg32p<<<(NN + 63) / 64, 256, 0, stream>>>(adj, indeg, gid, (const h8*)bufC, pool);
  // final: counts, mean, readout
  k_out<<<1, 256, 0, stream>>>(pool, gid, Wc, out);
}

// Round 12
// 205.980 us; speedup vs baseline: 1.0620x; 1.0256x over previous
//
#include <hip/hip_runtime.h>

#define NN 100000
#define NE 1600000
#define NG 64
#define D_IN 128
#define D_H 64
#define D_H2 32
#define D_OUT 16
#define SLOPE 0.01f
#define REC 48   // slots per node; tails cleaned to NN in-LDS by consumers

#define BSH 9                     // bucket = node >> 9 (512 nodes/bucket)  [R4 proven]
#define NBK 196                   // ceil(100000/512)
#define NCB 500                   // scatter blocks (chunk 3200 edges)
#define CHE (NE / NCB)            // 3200 edges per block
#define PCAP 48                   // per-(block,bucket) cap: lambda=16.3 +7.8sigma

typedef _Float16 half2v __attribute__((ext_vector_type(2)));
typedef _Float16 h8 __attribute__((ext_vector_type(8)));
typedef float f32x4 __attribute__((ext_vector_type(4)));

// ---------- P17: LDS write-combined build scatter (R9 WIN: keep) ------------
__global__ __launch_bounds__(512) void p12_scatter(const int* __restrict__ src,
                                                   const int* __restrict__ dst,
                                                   unsigned* __restrict__ pkD,
                                                   unsigned short* __restrict__ pkS,
                                                   int* __restrict__ cntD,
                                                   int* __restrict__ cntS,
                                                   float* __restrict__ pool) {
  __shared__ unsigned stD[NBK][PCAP];          // 37.6 KB
  __shared__ unsigned short stS[NBK][PCAP];    // 18.8 KB
  __shared__ int cD[NBK], cS[NBK];
  int b = blockIdx.x, t = threadIdx.x;
  if (b == 0) {
    for (int i = t; i < NG * D_H2; i += 512) pool[i] = 0.f;
  }
  for (int i = t; i < NBK; i += 512) { cD[i] = 0; cS[i] = 0; }
  __syncthreads();
  const int4* s4 = (const int4*)(src + b * CHE);
  const int4* d4 = (const int4*)(dst + b * CHE);
  for (int i = t; i < CHE / 4; i += 512) {
    int4 s = s4[i], d = d4[i];
#pragma unroll
    for (int j = 0; j < 4; ++j) {
      int ss = (j == 0) ? s.x : (j == 1) ? s.y : (j == 2) ? s.z : s.w;
      int dd = (j == 0) ? d.x : (j == 1) ? d.y : (j == 2) ? d.z : d.w;
      int kd = dd >> BSH;
      int pd = atomicAdd(&cD[kd], 1);
      if (pd < PCAP) stD[kd][pd] = ((unsigned)(dd & 511) << 17) | (unsigned)ss;
      int ks = ss >> BSH;
      int ps = atomicAdd(&cS[ks], 1);
      if (ps < PCAP) stS[ks][ps] = (unsigned short)(ss & 511);
    }
  }
  __syncthreads();
  int wid = t >> 6, lane = t & 63;
  for (int k = wid; k < NBK; k += 8) {
    int cd = min(cD[k], PCAP), cs = min(cS[k], PCAP);
    if (lane < cd) pkD[((size_t)k * NCB + b) * PCAP + lane] = stD[k][lane];
    if (lane < cs) pkS[((size_t)k * NCB + b) * PCAP + lane] = stS[k][lane];
  }
  for (int i = t; i < NBK; i += 512) {
    cntD[i * NCB + b] = min(cD[i], PCAP);
    cntS[i * NCB + b] = min(cS[i], PCAP);
  }
}

// ---------- P3: per-bucket adjacency + indeg (dst) / outdeg (src) -----------
__global__ __launch_bounds__(512) void p3_build(const unsigned* __restrict__ pkD,
                                                const unsigned short* __restrict__ pkS,
                                                const int* __restrict__ cntD,
                                                const int* __restrict__ cntS,
                                                int* __restrict__ adj,
                                                int* __restrict__ indeg,
                                                int* __restrict__ outdeg) {
  __shared__ int hh[512];
  int bb = blockIdx.x, t = threadIdx.x;
  hh[t] = 0;
  __syncthreads();
  if (bb < NBK) {
    int k = bb;
    int n0 = k << BSH;
    if (t < NCB) {
      int cnt = cntD[k * NCB + t];
      const uint4* r4 = (const uint4*)(pkD + ((size_t)k * NCB + t) * PCAP);
      for (int i = 0; i * 4 < cnt; ++i) {
        uint4 v = r4[i];
#pragma unroll
        for (int j = 0; j < 4; ++j) {
          int idx = i * 4 + j;
          if (idx < cnt) {
            unsigned rec = (j == 0) ? v.x : (j == 1) ? v.y : (j == 2) ? v.z : v.w;
            int local = rec >> 17;
            int pos = atomicAdd(&hh[local], 1);
            if (pos < REC) adj[(size_t)(n0 + local) * REC + pos] = (int)(rec & 0x1FFFF);
          }
        }
      }
    }
    __syncthreads();
    int n = n0 + t;
    if (n < NN) indeg[n] = hh[t];
  } else {
    int k = bb - NBK;
    if (t < NCB) {
      int cnt = cntS[k * NCB + t];
      const uint4* r4 = (const uint4*)(pkS + ((size_t)k * NCB + t) * PCAP);
      for (int i = 0; i * 8 < cnt; ++i) {
        uint4 v = r4[i];
        const unsigned short* u = (const unsigned short*)&v;
#pragma unroll
        for (int j = 0; j < 8; ++j) {
          int idx = i * 8 + j;
          if (idx < cnt) atomicAdd(&hh[u[j]], 1);
        }
      }
    }
    __syncthreads();
    int n0 = k << BSH;
    int n = n0 + t;
    if (n < NN) outdeg[n] = hh[t];
  }
}

// ---------- MFMA mm1: X fp32 [N,128] @ W1 [128,64] -> fp16, rsqrt(odeg) scale
__global__ __launch_bounds__(256) void k_mm1f(const float* __restrict__ X,
                                              const float* __restrict__ W,
                                              const int* __restrict__ odeg,
                                              _Float16* __restrict__ Y) {
  __shared__ _Float16 Wt[64][136];
  int t = threadIdx.x;
  if (blockIdx.x == 0 && t < 64) Y[(size_t)NN * 64 + t] = (_Float16)0.f;
  for (int i = t; i < 128 * 64; i += 256) {
    int k = i >> 6, f = i & 63;
    Wt[f][k] = (_Float16)W[i];
  }
  __syncthreads();
  int lane = t & 63, w = t >> 6;
  int m = lane & 15, q = lane >> 4;
  h8 bf[4][4];
#pragma unroll
  for (int kc = 0; kc < 4; ++kc)
#pragma unroll
    for (int nt = 0; nt < 4; ++nt)
      bf[kc][nt] = *(const h8*)&Wt[nt * 16 + m][kc * 32 + q * 8];

  const int NT = NN / 16;  // 6250
  int idx = blockIdx.x * 4 + w;
  int t0 = idx * 2, t1 = t0 + 1;
  f32x4 r0[8], r1[8];
  if (t0 < NT) {
    const f32x4* X0 = (const f32x4*)(X + (size_t)(t0 * 16 + m) * 128);
#pragma unroll
    for (int kc = 0; kc < 4; ++kc) {
      r0[kc * 2 + 0] = X0[kc * 8 + q * 2 + 0];
      r0[kc * 2 + 1] = X0[kc * 8 + q * 2 + 1];
    }
  }
  if (t1 < NT) {
    const f32x4* X1 = (const f32x4*)(X + (size_t)(t1 * 16 + m) * 128);
#pragma unroll
    for (int kc = 0; kc < 4; ++kc) {
      r1[kc * 2 + 0] = X1[kc * 8 + q * 2 + 0];
      r1[kc * 2 + 1] = X1[kc * 8 + q * 2 + 1];
    }
  }
#pragma unroll
  for (int half = 0; half < 2; ++half) {
    int tile = (half == 0) ? t0 : t1;
    if (tile >= NT) continue;
    f32x4* rr = (half == 0) ? r0 : r1;
    f32x4 acc[4] = {{0,0,0,0},{0,0,0,0},{0,0,0,0},{0,0,0,0}};
#pragma unroll
    for (int kc = 0; kc < 4; ++kc) {
      f32x4 x0 = rr[kc * 2 + 0], x1 = rr[kc * 2 + 1];
      h8 a;
      a[0] = (_Float16)x0.x; a[1] = (_Float16)x0.y;
      a[2] = (_Float16)x0.z; a[3] = (_Float16)x0.w;
      a[4] = (_Float16)x1.x; a[5] = (_Float16)x1.y;
      a[6] = (_Float16)x1.z; a[7] = (_Float16)x1.w;
#pragma unroll
      for (int nt = 0; nt < 4; ++nt)
        acc[nt] = __builtin_amdgcn_mfma_f32_16x16x32_f16(a, bf[kc][nt], acc[nt], 0, 0, 0);
    }
    int n0 = tile * 16;
#pragma unroll
    for (int reg = 0; reg < 4; ++reg) {
      int nn = n0 + q * 4 + reg;
      float sc = rsqrtf((float)max(odeg[nn], 1));
#pragma unroll
      for (int nt = 0; nt < 4; ++nt)
        Y[(size_t)nn * 64 + nt * 16 + m] = (_Float16)(acc[nt][reg] * sc);
    }
  }
}

// ---------- fused agg + mm2: block = 16 nodes, 128 threads (R11 WIN) --------
// Block-size gradient measured: 64n/512t = 46.5us, 32n/256t = 40.4us,
// 16n/128t = win. Many small blocks beat few fat blocks for latency-bound
// gathers: more independent streams/CU, narrower barriers.
__global__ __launch_bounds__(128)
void k_aggmm2(const int* __restrict__ adj,
              const int* __restrict__ indeg,
              const int* __restrict__ odeg,
              const h8* __restrict__ H8,
              const float* __restrict__ W,
              _Float16* __restrict__ Y) {
  __shared__ int Adj[16][REC];      // 3 KB
  __shared__ int Deg[16];
  __shared__ _Float16 Ht[16][72];   // 2.25 KB
  __shared__ _Float16 Wt[32][72];   // 4.5 KB
  int t = threadIdx.x;
  if (blockIdx.x == 0 && t < 32) Y[(size_t)NN * 32 + t] = (_Float16)0.f;
  for (int i = t; i < 64 * 32; i += 128) {
    int k = i >> 5, f = i & 31;
    Wt[f][k] = (_Float16)W[i];
  }
  int node0 = blockIdx.x * 16;   // NN % 16 == 0: blocks exactly cover
  {
    const int4* gadj = (const int4*)(adj + (size_t)node0 * REC);
    for (int i = t; i < 16 * (REC / 4); i += 128)
      ((int4*)Adj)[i] = gadj[i];
    if (t < 16) Deg[t] = indeg[node0 + t];
  }
  __syncthreads();
  // clean tail slots (garbage -> phantom NN); 16*48/128 = 6 iterations
  for (int i = t; i < 16 * REC; i += 128) {
    int ndc = i / REC, j = i % REC;
    if (j >= min(Deg[ndc], REC)) Adj[ndc][j] = NN;
  }
  __syncthreads();
  // phase A: gather + accumulate (8 threads/node, 16B octets)
  int l8 = t & 7;
  int nd = t >> 3;                // node in block, 0..15
  int deg = Deg[nd];
  int groups = (min(deg, REC) + 15) >> 4;
  float acc[8] = {0.f, 0.f, 0.f, 0.f, 0.f, 0.f, 0.f, 0.f};
  for (int g = 0; g < groups; ++g) {
    int4 c0 = *(const int4*)&Adj[nd][g * 16 + 0];
    int4 c1 = *(const int4*)&Adj[nd][g * 16 + 4];
    int4 c2 = *(const int4*)&Adj[nd][g * 16 + 8];
    int4 c3 = *(const int4*)&Adj[nd][g * 16 + 12];
    h8 v0 = H8[(size_t)c0.x * 8 + l8];
    h8 v1 = H8[(size_t)c0.y * 8 + l8];
    h8 v2 = H8[(size_t)c0.z * 8 + l8];
    h8 v3 = H8[(size_t)c0.w * 8 + l8];
    h8 v4 = H8[(size_t)c1.x * 8 + l8];
    h8 v5 = H8[(size_t)c1.y * 8 + l8];
    h8 v6 = H8[(size_t)c1.z * 8 + l8];
    h8 v7 = H8[(size_t)c1.w * 8 + l8];
    h8 v8 = H8[(size_t)c2.x * 8 + l8];
    h8 v9 = H8[(size_t)c2.y * 8 + l8];
    h8 va = H8[(size_t)c2.z * 8 + l8];
    h8 vb = H8[(size_t)c2.w * 8 + l8];
    h8 vc = H8[(size_t)c3.x * 8 + l8];
    h8 vd = H8[(size_t)c3.y * 8 + l8];
    h8 ve = H8[(size_t)c3.z * 8 + l8];
    h8 vf = H8[(size_t)c3.w * 8 + l8];
#pragma unroll
    for (int j = 0; j < 8; ++j)
      acc[j] += ((((float)v0[j] + (float)v1[j]) + ((float)v2[j] + (float)v3[j])) +
                 (((float)v4[j] + (float)v5[j]) + ((float)v6[j] + (float)v7[j]))) +
                ((((float)v8[j] + (float)v9[j]) + ((float)va[j] + (float)vb[j])) +
                 (((float)vc[j] + (float)vd[j]) + ((float)ve[j] + (float)vf[j])));
  }
  float sc = rsqrtf((float)max(deg, 1));
  h8 hv;
#pragma unroll
  for (int j = 0; j < 8; ++j) {
    float x = acc[j] * sc;
    hv[j] = (_Float16)((x > 0.f) ? x : SLOPE * x);
  }
  *(h8*)&Ht[nd][l8 * 8] = hv;
  __syncthreads();
  // phase B: 2 waves, wave w -> col-tile w; A = all 16 node-rows
  int lane = t & 63, w = t >> 6;
  int m = lane & 15, q = lane >> 4;
  h8 bf[2], af[2];
#pragma unroll
  for (int kc = 0; kc < 2; ++kc) {
    bf[kc] = *(const h8*)&Wt[w * 16 + m][kc * 32 + q * 8];
    af[kc] = *(const h8*)&Ht[m][kc * 32 + q * 8];
  }
  f32x4 acc2 = {0, 0, 0, 0};
#pragma unroll
  for (int kc = 0; kc < 2; ++kc)
    acc2 = __builtin_amdgcn_mfma_f32_16x16x32_f16(af[kc], bf[kc], acc2, 0, 0, 0);
#pragma unroll
  for (int reg = 0; reg < 4; ++reg) {
    int nn = node0 + q * 4 + reg;
    float sco = rsqrtf((float)max(odeg[nn], 1));
    Y[(size_t)nn * 32 + w * 16 + m] = (_Float16)(acc2[reg] * sco);
  }
}

// ---------- fused layer-2 aggregation + per-graph pool partials -------------
// R12: apply the measured small-block gradient here too: 64n/256t ->
// 32n/128t (4 threads/node unchanged -- h2 rows are 4 octets wide).
// NN % 32 == 0: all blocks full, valid-masking gone from the hot loop.
__global__ __launch_bounds__(128)
void k_agg32p(const int* __restrict__ adj,
              const int* __restrict__ indeg,
              const int* __restrict__ gid,
              const h8* __restrict__ H8,
              float* __restrict__ pool) {
  __shared__ int Adj2[32][REC];    // 6 KB
  __shared__ int Deg2[32];
  __shared__ float lp[4][D_H2];
  __shared__ int gmin_s;
  int t = threadIdx.x;
  int l4 = t & 3;                  // feature octet (8 halves = 16B)
  int nd = t >> 2;                 // node in block, 0..31
  int node0 = blockIdx.x * 32;     // NN % 32 == 0: never OOB
  int node = node0 + nd;
  if (t == 0) gmin_s = gid[node0];
  if (t < 4 * D_H2) ((float*)lp)[t] = 0.f;
  {
    const int4* gadj = (const int4*)(adj + (size_t)node0 * REC);
    for (int i = t; i < 32 * (REC / 4); i += 128)
      ((int4*)Adj2)[i] = gadj[i];
    if (t < 32) Deg2[t] = indeg[node0 + t];
  }
  __syncthreads();  // Adj2/Deg2 staged, lp zeroed, gmin_s set
  // clean tail slots (garbage -> phantom NN); 32*48/128 = 12 iterations
  for (int i = t; i < 32 * REC; i += 128) {
    int ndc = i / REC, j = i % REC;
    if (j >= min(Deg2[ndc], REC)) Adj2[ndc][j] = NN;
  }
  __syncthreads();
  int deg = Deg2[nd];
  int groups = (min(deg, REC) + 15) >> 4;
  float acc[8] = {0.f, 0.f, 0.f, 0.f, 0.f, 0.f, 0.f, 0.f};
  for (int g = 0; g < groups; ++g) {
    int4 c0 = *(const int4*)&Adj2[nd][g * 16 + 0];
    int4 c1 = *(const int4*)&Adj2[nd][g * 16 + 4];
    int4 c2 = *(const int4*)&Adj2[nd][g * 16 + 8];
    int4 c3 = *(const int4*)&Adj2[nd][g * 16 + 12];
    h8 v0 = H8[(size_t)c0.x * 4 + l4];
    h8 v1 = H8[(size_t)c0.y * 4 + l4];
    h8 v2 = H8[(size_t)c0.z * 4 + l4];
    h8 v3 = H8[(size_t)c0.w * 4 + l4];
    h8 v4 = H8[(size_t)c1.x * 4 + l4];
    h8 v5 = H8[(size_t)c1.y * 4 + l4];
    h8 v6 = H8[(size_t)c1.z * 4 + l4];
    h8 v7 = H8[(size_t)c1.w * 4 + l4];
    h8 v8 = H8[(size_t)c2.x * 4 + l4];
    h8 v9 = H8[(size_t)c2.y * 4 + l4];
    h8 va = H8[(size_t)c2.z * 4 + l4];
    h8 vb = H8[(size_t)c2.w * 4 + l4];
    h8 vc = H8[(size_t)c3.x * 4 + l4];
    h8 vd = H8[(size_t)c3.y * 4 + l4];
    h8 ve = H8[(size_t)c3.z * 4 + l4];
    h8 vf = H8[(size_t)c3.w * 4 + l4];
#pragma unroll
    for (int j = 0; j < 8; ++j)
      acc[j] += ((((float)v0[j] + (float)v1[j]) + ((float)v2[j] + (float)v3[j])) +
                 (((float)v4[j] + (float)v5[j]) + ((float)v6[j] + (float)v7[j]))) +
                ((((float)v8[j] + (float)v9[j]) + ((float)va[j] + (float)vb[j])) +
                 (((float)vc[j] + (float)vd[j]) + ((float)ve[j] + (float)vf[j])));
  }
  {
    float sc = rsqrtf((float)max(deg, 1));
    int gl = min(gid[node] - gmin_s, 3);
#pragma unroll
    for (int j = 0; j < 8; ++j) {
      float x = acc[j] * sc;
      x = (x > 0.f) ? x : SLOPE * x;   // h3 element, fp32
      atomicAdd(&lp[gl][l4 * 8 + j], x);
    }
  }
  __syncthreads();
  // flush: thread t covers (gl, feat) -- exactly 128 slots
  {
    float v = ((float*)lp)[t];
    if (v != 0.f) {
      int gl = t >> 5, f = t & 31;
      atomicAdd(&pool[(gmin_s + gl) * D_H2 + f], v);
    }
  }
}

// ---------- final: counts via binary search, mean, @ Wc ---------------------
__global__ __launch_bounds__(256) void k_out(const float* __restrict__ pool,
                                             const int* __restrict__ gid,
                                             const float* __restrict__ Wc,
                                             float* __restrict__ out) {
  __shared__ int bnd[NG + 1];
  __shared__ float mean[NG][D_H2];
  int t = threadIdx.x;
  if (t <= NG) {
    int target = t;  // lower_bound(gid, target)
    int lo = 0, hi = NN;
    while (lo < hi) {
      int mid = (lo + hi) >> 1;
      if (gid[mid] < target) lo = mid + 1; else hi = mid;
    }
    bnd[t] = lo;
  }
  __syncthreads();
  for (int i = t; i < NG * D_H2; i += 256) {
    int g = i >> 5;
    float inv = 1.0f / (float)max(bnd[g + 1] - bnd[g], 1);
    ((float*)mean)[i] = pool[i] * inv;
  }
  __syncthreads();
  for (int i = t; i < NG * D_OUT; i += 256) {
    int g = i / D_OUT, o = i % D_OUT;
    float s = 0.f;
#pragma unroll
    for (int c = 0; c < D_H2; ++c) s += mean[g][c] * Wc[c * D_OUT + o];
    out[i] = s;
  }
}

extern "C" void kernel_launch(void* const* d_in, const int* in_sizes, int n_in,
                              void* d_out, int out_size, void* d_ws, size_t ws_size,
                              hipStream_t stream) {
  const float* X  = (const float*)d_in[0];
  const int*   src = (const int*)d_in[1];
  const int*   dst = (const int*)d_in[2];
  const int*   gid = (const int*)d_in[3];
  const float* W1 = (const float*)d_in[4];
  const float* W2 = (const float*)d_in[5];
  const float* Wc = (const float*)d_in[6];
  float* out = (float*)d_out;

  char* p = (char*)d_ws;
  auto alloc = [&](size_t bytes) {
    char* q = p;
    p += (bytes + 255) & ~(size_t)255;
    return q;
  };
  float*          pool   = (float*)alloc(NG * D_H2 * 4);                 // 8 KB
  int*            outdeg = (int*)alloc(NN * 4);
  int*            indeg  = (int*)alloc(NN * 4);
  int*            cntD   = (int*)alloc((size_t)NBK * NCB * 4);           // 392 KB
  int*            cntS   = (int*)alloc((size_t)NBK * NCB * 4);           // 392 KB
  unsigned*       pkD    = (unsigned*)alloc((size_t)NBK * NCB * PCAP * 4);       // 18.8 MB
  unsigned short* pkS    = (unsigned short*)alloc((size_t)NBK * NCB * PCAP * 2); // 9.4 MB
  int*            adj    = (int*)alloc((size_t)NN * REC * 4);            // 19.2 MB
  _Float16*       bufA   = (_Float16*)alloc((size_t)(NN + 1) * 64 * 2);  // h0 (+phantom)
  _Float16*       bufC   = (_Float16*)alloc((size_t)(NN + 1) * 32 * 2);  // h2 (+phantom)

  // single-pass build into private (block,bucket) regions (pool zeroed inside)
  p12_scatter<<<NCB, 512, 0, stream>>>(src, dst, pkD, pkS, cntD, cntS, pool);
  p3_build<<<2 * NBK, 512, 0, stream>>>(pkD, pkS, cntD, cntS, adj, indeg, outdeg);

  // layer 1 matmul: h0 = (X @ W1) * rsqrt(outdeg)   (phantom row zeroed)
  k_mm1f<<<782, 256, 0, stream>>>(X, W1, outdeg, bufA);
  // fused: h1 = leaky(rsqrt(indeg) * A h0); h2 = (h1 @ W2) * rsqrt(outdeg)
  k_aggmm2<<<NN / 16, 128, 0, stream>>>(adj, indeg, outdeg, (const h8*)bufA, W2, bufC);
  // fused: h3 = leaky(rsqrt(indeg) * A h2) -> per-graph pool partials (no h3 in HBM)
  k_agg32p<<<NN / 32, 128, 0, stream>>>(adj, indeg, gid, (const h8*)bufC, pool);
  // final: counts, mean, readout
  k_out<<<1, 256, 0, stream>>>(pool, gid, Wc, out);
}